// Round 9
// baseline (279.976 us; speedup 1.0000x reference)
//
#include <hip/hip_runtime.h>
#include <hip/hip_bf16.h>
#include <math.h>

#define BLOCK 256
#define IMG 512
#define SW 88                   // staged bf16 stride (176 B: 16B-aligned b128 frags)
#define RSTR 40                 // ring bf16 stride per col (80 B, 16B-aligned, 2-way banks)
#define NBLOCKS 3072            // 96 planes * 8 col-tiles * 4 row-chunks
#define NACC 128
#define N_TOTAL 25165824.0f

typedef float f32x4 __attribute__((ext_vector_type(4)));
typedef short s16x8 __attribute__((ext_vector_type(8)));

struct WB { unsigned short b[11]; float c2; float k1; float k2; };
union FR { unsigned int u[4]; s16x8 s; };

// bf16 pack, round-half-up: 2 adds + 1 v_perm (vs ~6-instr RNE library path).
// All packed values are non-negative finite, so the integer bias is safe.
__device__ __forceinline__ unsigned int pk2(float a, float b) {
    const unsigned int ua = __float_as_uint(a) + 0x8000u;
    const unsigned int ub = __float_as_uint(b) + 0x8000u;
    return __builtin_amdgcn_perm(ub, ua, 0x07060302u);   // {hi16(b), hi16(a)}
}

// Force v into VGPRs at this program point (defeats load sinking).
__device__ __forceinline__ void pin4(float4& v) {
    asm volatile("" : "+v"(v.x), "+v"(v.y), "+v"(v.z), "+v"(v.w));
}

__device__ __forceinline__ void stage5(unsigned short (*sq)[16][SW],
                                       int r, int i, float4 xv, float4 yv) {
    *(uint2*)&sq[0][r][4*i] = make_uint2(pk2(xv.x,xv.y), pk2(xv.z,xv.w));
    *(uint2*)&sq[1][r][4*i] = make_uint2(pk2(yv.x,yv.y), pk2(yv.z,yv.w));
    *(uint2*)&sq[2][r][4*i] = make_uint2(pk2(xv.x*xv.x,xv.y*xv.y), pk2(xv.z*xv.z,xv.w*xv.w));
    *(uint2*)&sq[3][r][4*i] = make_uint2(pk2(yv.x*yv.x,yv.y*yv.y), pk2(yv.z*yv.z,yv.w*yv.w));
    *(uint2*)&sq[4][r][4*i] = make_uint2(pk2(xv.x*yv.x,xv.y*yv.y), pk2(xv.z*yv.z,xv.w*yv.w));
}

__device__ __forceinline__ void load_set(const float* __restrict__ P,
                                         const float* __restrict__ T,
                                         int R0, int step,
                                         int rA, int colA, bool okcA,
                                         bool hasB, int rB, int colB, bool okcB,
                                         float4& xA, float4& yA, float4& xB, float4& yB) {
    const int gr = R0 - 5 + 16 * step + rA;
    if (okcA && gr >= 0 && gr < IMG) {
        xA = *(const float4*)(P + ((size_t)gr << 9) + colA);
        yA = *(const float4*)(T + ((size_t)gr << 9) + colA);
    } else { xA = make_float4(0,0,0,0); yA = make_float4(0,0,0,0); }
    const int grB = R0 - 5 + 16 * step + rB;
    if (hasB && okcB && grB >= 0 && grB < IMG) {
        xB = *(const float4*)(P + ((size_t)grB << 9) + colB);
        yB = *(const float4*)(T + ((size_t)grB << 9) + colB);
    } else { xB = make_float4(0,0,0,0); yB = make_float4(0,0,0,0); }
}

__global__ __launch_bounds__(BLOCK, 3)
void ssim_tiled(const float* __restrict__ pred,
                const float* __restrict__ targ,
                float* __restrict__ accum, WB wb) {
    __shared__ unsigned short s_w[3][16][32];      // 3 KB
    __shared__ unsigned short s_q[5][16][SW];      // 14.1 KB
    __shared__ unsigned short s_ring[5][64][RSTR]; // 25.6 KB

    const int tid = threadIdx.x;
    for (int e = tid; e < 3 * 512; e += BLOCK) {
        const int mat = e >> 9;
        const int m   = (e >> 5) & 15;
        const int k   = e & 31;
        int idx;
        if (mat == 0) idx = k - m - 3;
        else          idx = (k - m - (mat == 2 ? 16 : 0)) & 31;
        s_w[mat][m][k] = (idx >= 0 && idx <= 10) ? wb.b[idx] : (unsigned short)0;
    }

    const int bx    = blockIdx.x;
    const int plane = bx >> 5;
    const int rem   = bx & 31;
    const int tx    = rem >> 2;
    const int ry    = rem & 3;
    const int C0    = tx * 64;
    const int R0    = ry * 128;

    const float* P = pred + (size_t)plane * (IMG * IMG);
    const float* T = targ + (size_t)plane * (IMG * IMG);

    const int w    = tid >> 6;
    const int lane = tid & 63;
    const int l15  = lane & 15;
    const int quad = lane >> 4;

    const int slotA = w * 80 + lane;
    const int rA = slotA / 20, iA = slotA % 20;
    const int colA = C0 - 8 + 4 * iA;
    const bool okcA = (colA >= 0) && (colA + 4 <= IMG);
    const bool hasB = (lane < 16);
    const int slotB = w * 80 + 64 + l15;
    const int rB = slotB / 20, iB = slotB % 20;
    const int colB = C0 - 8 + 4 * iB;
    const bool okcB = (colB >= 0) && (colB + 4 <= IMG);

    const float c2 = wb.c2, K1 = wb.k1, K2 = wb.k2;
    const f32x4 z = {0.f, 0.f, 0.f, 0.f};
    float lsum = 0.f;

    // ---- prologue: step-0 set (staged now) + step-1 set (held, pinned) ----
    float4 pxA, pyA, pxB, pyB;
    load_set(P, T, R0, 0, rA, colA, okcA, hasB, rB, colB, okcB, pxA, pyA, pxB, pyB);
    float4 sxA[2], syA[2], sxB[2], syB[2];
    load_set(P, T, R0, 1, rA, colA, okcA, hasB, rB, colB, okcB,
             sxA[1], syA[1], sxB[1], syB[1]);
    pin4(sxA[1]); pin4(syA[1]); pin4(sxB[1]); pin4(syB[1]);
    __syncthreads();               // s_w ready

    FR bw;  bw.s  = *(const s16x8*)&s_w[0][l15][quad * 8];
    FR aw0; aw0.s = *(const s16x8*)&s_w[1][l15][quad * 8];
    FR aw1; aw1.s = *(const s16x8*)&s_w[2][l15][quad * 8];

    stage5(s_q, rA, iA, pxA, pyA);
    if (hasB) stage5(s_q, rB, iB, pxB, pyB);
    __syncthreads();               // s_q(step0) ready

    const int rcol = 16 * w + l15;

#pragma unroll
    for (int s = 0; s < 9; ++s) {
        // ---- issue loads for step s+2 and PIN them (real prefetch distance 2) ----
        if (s < 7) {
            load_set(P, T, R0, s + 2, rA, colA, okcA, hasB, rB, colB, okcB,
                     sxA[s & 1], syA[s & 1], sxB[s & 1], syB[s & 1]);
            pin4(sxA[s & 1]); pin4(syA[s & 1]); pin4(sxB[s & 1]); pin4(syB[s & 1]);
        }

        // ---- H: 5 b128 A-reads + 5 MFMA -> wave-private ring ----
        {
            FR a0, a1, a2, a3, a4;
            a0.s = *(const s16x8*)&s_q[0][l15][16*w + 8*quad];
            a1.s = *(const s16x8*)&s_q[1][l15][16*w + 8*quad];
            a2.s = *(const s16x8*)&s_q[2][l15][16*w + 8*quad];
            a3.s = *(const s16x8*)&s_q[3][l15][16*w + 8*quad];
            a4.s = *(const s16x8*)&s_q[4][l15][16*w + 8*quad];
            f32x4 d0 = __builtin_amdgcn_mfma_f32_16x16x32_bf16(a0.s, bw.s, z, 0, 0, 0);
            f32x4 d1 = __builtin_amdgcn_mfma_f32_16x16x32_bf16(a1.s, bw.s, z, 0, 0, 0);
            f32x4 d2 = __builtin_amdgcn_mfma_f32_16x16x32_bf16(a2.s, bw.s, z, 0, 0, 0);
            f32x4 d3 = __builtin_amdgcn_mfma_f32_16x16x32_bf16(a3.s, bw.s, z, 0, 0, 0);
            f32x4 d4 = __builtin_amdgcn_mfma_f32_16x16x32_bf16(a4.s, bw.s, z, 0, 0, 0);
            const int pb = (16 * s + 4 * quad) & 31;
            *(uint2*)&s_ring[0][rcol][pb] = make_uint2(pk2(d0[0],d0[1]), pk2(d0[2],d0[3]));
            *(uint2*)&s_ring[1][rcol][pb] = make_uint2(pk2(d1[0],d1[1]), pk2(d1[2],d1[3]));
            *(uint2*)&s_ring[2][rcol][pb] = make_uint2(pk2(d2[0],d2[1]), pk2(d2[2],d2[3]));
            *(uint2*)&s_ring[3][rcol][pb] = make_uint2(pk2(d3[0],d3[1]), pk2(d3[2],d3[3]));
            *(uint2*)&s_ring[4][rcol][pb] = make_uint2(pk2(d4[0],d4[1]), pk2(d4[2],d4[3]));
        }

        // ---- V: out rows [R0+16t, +16) for t=s-1 ----
        if (s >= 1) {
            const FR aw = ((s - 1) & 1) ? aw1 : aw0;
            f32x4 acc[5];
#pragma unroll
            for (int q = 0; q < 5; ++q) {
                FR b; b.s = *(const s16x8*)&s_ring[q][rcol][quad * 8];
                acc[q] = __builtin_amdgcn_mfma_f32_16x16x32_bf16(aw.s, b.s, z, 0, 0, 0);
            }
#pragma unroll
            for (int i = 0; i < 4; ++i) {
                const float u1  = acc[0][i];
                const float u2  = acc[1][i];
                const float m11 = u1 * u1;
                const float m22 = u2 * u2;
                const float m12 = u1 * u2;
                const float e11 = acc[2][i] * c2;
                const float e22 = acc[3][i] * c2;
                const float e12 = acc[4][i] * c2;
                const float A = fmaf(2.f, m12, K1);
                const float B = fmaf(2.f, e12 - m12, K2);
                const float C = m11 + m22 + K1;
                const float D = (e11 + e22) - (m11 + m22) + K2;
                lsum = fmaf(A * B, __builtin_amdgcn_rcpf(C * D), lsum);
            }
        }

        __syncthreads();           // consumers done with s_q(step s)

        // ---- stage set for step s+1 (loaded at iteration s-1) ----
        if (s < 8) {
            stage5(s_q, rA, iA, sxA[(s + 1) & 1], syA[(s + 1) & 1]);
            if (hasB) stage5(s_q, rB, iB, sxB[(s + 1) & 1], syB[(s + 1) & 1]);
            __syncthreads();
        }
    }

#pragma unroll
    for (int off = 32; off > 0; off >>= 1) lsum += __shfl_down(lsum, off, 64);
    if (lane == 0) atomicAdd(&accum[(bx * 4 + w) & (NACC - 1)], lsum);
}

__global__ void ssim_finalize(const float* __restrict__ accum, float* __restrict__ out) {
    const int l = threadIdx.x;
    float v = accum[l] + accum[l + 64];
#pragma unroll
    for (int off = 32; off > 0; off >>= 1) v += __shfl_down(v, off, 64);
    if (l == 0) out[0] = 1.0f - v * (1.0f / N_TOTAL);
}

extern "C" void kernel_launch(void* const* d_in, const int* in_sizes, int n_in,
                              void* d_out, int out_size, void* d_ws, size_t ws_size,
                              hipStream_t stream) {
    const float* pred = (const float*)d_in[0];
    const float* targ = (const float*)d_in[1];
    float* out = (float*)d_out;
    float* ws  = (float*)d_ws;

    WB wb;
    {
        double gg[11], sum = 0.0;
        for (int k = 0; k < 11; ++k) {
            const double d = (double)(k - 5);
            gg[k] = exp(-d * d / 4.5);
            sum += gg[k];
        }
        double sbf = 0.0;
        for (int k = 0; k < 11; ++k) {
            union { float f; unsigned int u; } cv;
            cv.f = (float)(gg[k] / sum);
            const unsigned int r = (cv.u + 0x7fffu + ((cv.u >> 16) & 1u)) >> 16;
            wb.b[k] = (unsigned short)r;
            union { float f; unsigned int u; } bk;
            bk.u = r << 16;
            sbf += (double)bk.f;
        }
        const double s2 = sbf * sbf;       // acc = s2 * true value
        wb.c2 = (float)s2;
        wb.k1 = (float)(0.0001 * s2 * s2); // C1 in acc^2 units
        wb.k2 = (float)(0.0009 * s2 * s2); // C2 in acc^2 units
    }

    hipMemsetAsync(ws, 0, NACC * sizeof(float), stream);
    ssim_tiled<<<NBLOCKS, BLOCK, 0, stream>>>(pred, targ, ws, wb);
    ssim_finalize<<<1, 64, 0, stream>>>(ws, out);
}